// Round 7
// baseline (269.033 us; speedup 1.0000x reference)
//
#include <hip/hip_runtime.h>

// Butterfly multiply (untied), n=1024, 10 stages, increasing stride, + bias.
//
// R7: 256-thread blocks (VGPR-safe empirically: R1=120, R4=256 — vs every
// 1024-thread variant stuck at 64 + spill). Tile = 16 rows per block.
// Thread t: wave w=t>>6, lane l=t&63; row = l&15, c = l>>4, chunk = w*4+c.
// Thread holds elements [chunk*64, chunk*64+64) of its row in v[64].
//   ls=0..5 : in-thread (pairs local to the 64-block), twiddle float4 loads
//             uniform per 16-lane group (pairs [32*chunk, 32*chunk+32)).
//   ls=6,7  : partner = chunk^1 / chunk^2 = lane^16 / lane^32 -> __shfl_xor.
//   ls=8,9  : partner = w^1 / w^2 -> sliced LDS exchange (16 KB, swizzled).
//   I/O     : LDS transpose slices (16 rows x 256 cols = 16 KB), swizzle
//             slot ^= row&7; HBM side perfectly coalesced dwordx4.
// All v[] indexing static via template unrolling (no macro _Pragma).

constexpr int N = 1024;

template<int LS>
__device__ __forceinline__ void inthread_stage(float (&v)[64],
                                               const float* __restrict__ twb)
{
    // twb = tw + LS*2048 + chunk*128 ; local pair p -> elements k0,k1
    #pragma unroll
    for (int p = 0; p < 32; ++p) {
        const int k0 = ((p >> LS) << (LS + 1)) | (p & ((1 << LS) - 1));
        const int k1 = k0 + (1 << LS);
        const float4 t = *reinterpret_cast<const float4*>(twb + p * 4);
        const float a = v[k0], b = v[k1];
        v[k0] = t.x * a + t.y * b;
        v[k1] = t.z * a + t.w * b;
    }
}

template<int LANEMASK>
__device__ __forceinline__ void shfl_stage(float (&v)[64],
                                           const float* __restrict__ twb,
                                           int ipos)
{
    // twb = tw + LS*2048 + p0*4 + 2*ipos ; per-k float2 = (own,partner) coeffs
    #pragma unroll
    for (int k = 0; k < 64; ++k) {
        const float2 t = *reinterpret_cast<const float2*>(twb + k * 4);
        const float co = ipos ? t.y : t.x;
        const float cp = ipos ? t.x : t.y;
        const float part = __shfl_xor(v[k], LANEMASK, 64);
        v[k] = co * v[k] + cp * part;
    }
}

template<int TIDMASK>
__device__ __forceinline__ void lds_stage(float (&v)[64],
                                          const float* __restrict__ twb,
                                          int ipos, int tid, float4* ex)
{
    const int swz  = (tid >> 1) & 3;   // same for tid^TIDMASK (mask >= 64)
    #pragma unroll
    for (int sl = 0; sl < 4; ++sl) {
        __syncthreads();
        #pragma unroll
        for (int Q = 0; Q < 4; ++Q) {
            const int k = sl * 16 + Q * 4;
            ex[tid * 4 + (Q ^ swz)] = make_float4(v[k], v[k+1], v[k+2], v[k+3]);
        }
        __syncthreads();
        float4 pq[4];
        #pragma unroll
        for (int Q = 0; Q < 4; ++Q)
            pq[Q] = ex[(tid ^ TIDMASK) * 4 + (Q ^ swz)];
        #pragma unroll
        for (int q = 0; q < 16; ++q) {
            const int k = sl * 16 + q;
            const float4 P = pq[q >> 2];
            const float pa = (q & 3) == 0 ? P.x : (q & 3) == 1 ? P.y
                           : (q & 3) == 2 ? P.z : P.w;
            const float2 t = *reinterpret_cast<const float2*>(twb + k * 4);
            const float co = ipos ? t.y : t.x;
            const float cp = ipos ? t.x : t.y;
            v[k] = co * v[k] + cp * pa;
        }
    }
}

__global__ __attribute__((amdgpu_flat_work_group_size(256, 256),
                          amdgpu_waves_per_eu(1, 4)))
void butterfly_kernel(const float* __restrict__ x,
                      const float* __restrict__ tw,
                      const float* __restrict__ bias,
                      float* __restrict__ out,
                      int batch)
{
    __shared__ __align__(16) float lds[4096];     // 16 KB
    float4* const ex = reinterpret_cast<float4*>(lds);

    const int tid = (int)threadIdx.x;
    const int l   = tid & 63;
    const int w   = tid >> 6;        // wave 0..3
    const int c   = l >> 4;          // sub-chunk 0..3
    const int row = l & 15;          // row within tile
    const int chunk = w * 4 + c;     // 0..15
    const int row0 = (int)blockIdx.x * 16;

    float v[64];

    // ================= IN: global -> LDS transpose slice -> registers ======
    // slice s = cols [256s, 256s+256); wave w consumes slice s == w.
    float4 tmp[4];
    #pragma unroll
    for (int rr = 0; rr < 4; ++rr) {
        int rg = row0 + rr * 4 + w; if (rg >= batch) rg = batch - 1;
        tmp[rr] = reinterpret_cast<const float4*>(x + (size_t)rg * N)[l];
    }
    #pragma unroll
    for (int s = 0; s < 4; ++s) {
        __syncthreads();
        #pragma unroll
        for (int rr = 0; rr < 4; ++rr) {
            const int R = rr * 4 + w;
            ex[R * 64 + (l ^ (R & 7))] = tmp[rr];
        }
        __syncthreads();
        if (s < 3) {
            #pragma unroll
            for (int rr = 0; rr < 4; ++rr) {
                int rg = row0 + rr * 4 + w; if (rg >= batch) rg = batch - 1;
                tmp[rr] = reinterpret_cast<const float4*>(
                    x + (size_t)rg * N + (s + 1) * 256)[l];
            }
        }
        if (w == s) {
            #pragma unroll
            for (int q = 0; q < 16; ++q) {
                const float4 t = ex[row * 64 + ((c * 16 + q) ^ (row & 7))];
                v[q*4+0] = t.x; v[q*4+1] = t.y;
                v[q*4+2] = t.z; v[q*4+3] = t.w;
            }
        }
    }

    // ================= stages 0..5: in-thread ==============================
    inthread_stage<0>(v, tw + 0 * 2048 + chunk * 128);
    inthread_stage<1>(v, tw + 1 * 2048 + chunk * 128);
    inthread_stage<2>(v, tw + 2 * 2048 + chunk * 128);
    inthread_stage<3>(v, tw + 3 * 2048 + chunk * 128);
    inthread_stage<4>(v, tw + 4 * 2048 + chunk * 128);
    inthread_stage<5>(v, tw + 5 * 2048 + chunk * 128);

    // ================= stages 6,7: cross-lane shfl =========================
    {   // ls=6: p = (chunk>>1)*64 + k ; ipos = chunk&1 ; partner lane^16
        const int ipos = chunk & 1;
        shfl_stage<16>(v, tw + 6 * 2048 + (chunk >> 1) * 256 + 2 * ipos, ipos);
    }
    {   // ls=7: p = (chunk>>2)*128 + (chunk&1)*64 + k ; ipos = (chunk>>1)&1
        const int ipos = (chunk >> 1) & 1;
        shfl_stage<32>(v, tw + 7 * 2048 + ((chunk >> 2) * 128 + (chunk & 1) * 64) * 4
                          + 2 * ipos, ipos);
    }

    // ================= stages 8,9: cross-wave LDS exchange =================
    {   // ls=8: p = (w>>1)*256 + c*64 + k ; ipos = w&1 ; partner tid^64
        const int ipos = w & 1;
        lds_stage<64>(v, tw + 8 * 2048 + ((w >> 1) * 256 + c * 64) * 4 + 2 * ipos,
                      ipos, tid, ex);
    }
    {   // ls=9: p = (w&1)*256 + c*64 + k ; ipos = (w>>1)&1 ; partner tid^128
        const int ipos = (w >> 1) & 1;
        lds_stage<128>(v, tw + 9 * 2048 + ((w & 1) * 256 + c * 64) * 4 + 2 * ipos,
                       ipos, tid, ex);
    }

    // ================= bias ================================================
    #pragma unroll
    for (int q = 0; q < 16; ++q) {
        const float4 b = *reinterpret_cast<const float4*>(bias + chunk * 64 + q * 4);
        v[q*4+0] += b.x; v[q*4+1] += b.y; v[q*4+2] += b.z; v[q*4+3] += b.w;
    }

    // ================= OUT: registers -> LDS slice -> global ===============
    #pragma unroll
    for (int s = 0; s < 4; ++s) {
        __syncthreads();
        if (w == s) {
            #pragma unroll
            for (int q = 0; q < 16; ++q)
                ex[row * 64 + ((c * 16 + q) ^ (row & 7))] =
                    make_float4(v[q*4], v[q*4+1], v[q*4+2], v[q*4+3]);
        }
        __syncthreads();
        #pragma unroll
        for (int rr = 0; rr < 4; ++rr) {
            const int R  = rr * 4 + w;
            const int rg = row0 + R;
            const float4 t = ex[R * 64 + (l ^ (R & 7))];
            if (rg < batch)
                reinterpret_cast<float4*>(out + (size_t)rg * N + s * 256)[l] = t;
        }
    }
}

extern "C" void kernel_launch(void* const* d_in, const int* in_sizes, int n_in,
                              void* d_out, int out_size, void* d_ws, size_t ws_size,
                              hipStream_t stream)
{
    (void)n_in; (void)d_ws; (void)ws_size; (void)out_size;
    const float* x    = (const float*)d_in[0];
    const float* tw   = (const float*)d_in[1];
    const float* bias = (const float*)d_in[2];
    float* out        = (float*)d_out;

    const int batch  = in_sizes[0] / N;
    const int blocks = (batch + 15) / 16;          // 2048 for batch=32768
    hipLaunchKernelGGL(butterfly_kernel, dim3(blocks), dim3(256), 0, stream,
                       x, tw, bias, out, batch);
}

// Round 8
// 100.177 us; speedup vs baseline: 2.6856x; 2.6856x over previous
//
#include <hip/hip_runtime.h>

// Butterfly multiply (untied), n=1024, 10 stages, increasing stride, + bias.
//
// R8 = R1 skeleton (proven 79.5 us, VGPR-clean) with ROWS=8 and a relaxed
// register budget. Rationale: R7 proved twiddle-load COUNT per row is the
// controlling variable (1 row/thread -> 448 loads -> 269 us; 4 rows/thread
// -> ~40 loads -> 79 us). ROWS=8 halves loads/row again and gives each
// scattered L2 twiddle load 8 independent FMA chains of ILP.
// Register math: 8*16 = 128 data floats + ~60 temps < 256; attributes
// amdgpu_flat_work_group_size(256,256) + amdgpu_waves_per_eu(1,4) let the
// allocator take what it needs (R4: 256 VGPR granted this way). NO
// __launch_bounds__ second arg (that pinned 128 -> spill in R2/R3).
//
// Layout per wave: element e = i*256 + lane*4 + j (i,j in 0..3), slot s=i*4+j.
//   ls=0,1  : in-thread (j bits), float4 twiddle
//   ls=2..7 : cross-lane via __shfl_xor mask 1..32, float2 twiddle
//   ls=8,9  : in-thread (i bits), float4 twiddle

constexpr int ROWS  = 8;    // rows per wave
constexpr int WAVES = 4;    // 256 threads per block
constexpr int N     = 1024;

__device__ __forceinline__ void pair_update(float (&v)[ROWS][16], int s0, int s1,
                                            const float4 t4)
{
    #pragma unroll
    for (int r = 0; r < ROWS; ++r) {
        const float x0 = v[r][s0], x1 = v[r][s1];
        v[r][s0] = t4.x * x0 + t4.y * x1;
        v[r][s1] = t4.z * x0 + t4.w * x1;
    }
}

template<int LS>
__device__ __forceinline__ void cross_stage(float (&v)[ROWS][16],
                                            const float* __restrict__ tw,
                                            int lane)
{
    constexpr int m = 1 << (LS - 2);              // lane xor mask
    const int ipos = (lane >> (LS - 2)) & 1;      // which half of the pair
    const float* __restrict__ base = tw + LS * 2048;
    #pragma unroll
    for (int i = 0; i < 4; ++i) {
        #pragma unroll
        for (int j = 0; j < 4; ++j) {
            const int e    = i * 256 + lane * 4 + j;
            const int pair = ((e >> (LS + 1)) << LS) | (e & ((1 << LS) - 1));
            const float2 t2 = *reinterpret_cast<const float2*>(
                base + (size_t)pair * 4 + ipos * 2);
            const float ta = ipos ? t2.y : t2.x;  // coeff of own value
            const float tb = ipos ? t2.x : t2.y;  // coeff of partner value
            const int s = i * 4 + j;
            #pragma unroll
            for (int r = 0; r < ROWS; ++r) {
                const float own  = v[r][s];
                const float part = __shfl_xor(own, m, 64);
                v[r][s] = ta * own + tb * part;
            }
        }
    }
}

__global__ __attribute__((amdgpu_flat_work_group_size(256, 256),
                          amdgpu_waves_per_eu(1, 4)))
void butterfly_kernel(const float* __restrict__ x,
                      const float* __restrict__ tw,
                      const float* __restrict__ bias,
                      float* __restrict__ out,
                      int batch)
{
    const int lane = (int)(threadIdx.x & 63u);
    const int wave = (int)(threadIdx.x >> 6u);
    const int row0 = (blockIdx.x * WAVES + wave) * ROWS;
    if (row0 >= batch) return;

    float v[ROWS][16];

    // ---- load: v[r][i*4+j] = x[row][i*256 + lane*4 + j] (coalesced dwordx4)
    #pragma unroll
    for (int r = 0; r < ROWS; ++r) {
        const int row = (row0 + r < batch) ? (row0 + r) : (batch - 1);
        const float4* __restrict__ src =
            reinterpret_cast<const float4*>(x + (size_t)row * N);
        #pragma unroll
        for (int i = 0; i < 4; ++i) {
            const float4 t = src[i * 64 + lane];
            v[r][i*4+0] = t.x; v[r][i*4+1] = t.y;
            v[r][i*4+2] = t.z; v[r][i*4+3] = t.w;
        }
    }

    // ---- ls = 0 (stride 1): pair = i*128 + lane*2 + jj
    #pragma unroll
    for (int i = 0; i < 4; ++i) {
        #pragma unroll
        for (int jj = 0; jj < 2; ++jj) {
            const int pair = i * 128 + lane * 2 + jj;
            const float4 t4 = *reinterpret_cast<const float4*>(tw + (size_t)pair * 4);
            pair_update(v, i*4 + jj*2, i*4 + jj*2 + 1, t4);
        }
    }

    // ---- ls = 1 (stride 2): pair = i*128 + lane*2 + j
    #pragma unroll
    for (int i = 0; i < 4; ++i) {
        #pragma unroll
        for (int j = 0; j < 2; ++j) {
            const int pair = i * 128 + lane * 2 + j;
            const float4 t4 = *reinterpret_cast<const float4*>(tw + 2048 + (size_t)pair * 4);
            pair_update(v, i*4 + j, i*4 + j + 2, t4);
        }
    }

    // ---- ls = 2..7 (stride 4..128): cross-lane
    cross_stage<2>(v, tw, lane);
    cross_stage<3>(v, tw, lane);
    cross_stage<4>(v, tw, lane);
    cross_stage<5>(v, tw, lane);
    cross_stage<6>(v, tw, lane);
    cross_stage<7>(v, tw, lane);

    // ---- ls = 8 (stride 256): pair = ih*256 + lane*4 + j
    #pragma unroll
    for (int ih = 0; ih < 2; ++ih) {
        #pragma unroll
        for (int j = 0; j < 4; ++j) {
            const int pair = ih * 256 + lane * 4 + j;
            const float4 t4 = *reinterpret_cast<const float4*>(tw + 8*2048 + (size_t)pair * 4);
            pair_update(v, ih*8 + j, ih*8 + 4 + j, t4);
        }
    }

    // ---- ls = 9 (stride 512): pair = i*256 + lane*4 + j
    #pragma unroll
    for (int i = 0; i < 2; ++i) {
        #pragma unroll
        for (int j = 0; j < 4; ++j) {
            const int pair = i * 256 + lane * 4 + j;
            const float4 t4 = *reinterpret_cast<const float4*>(tw + 9*2048 + (size_t)pair * 4);
            pair_update(v, i*4 + j, i*4 + 8 + j, t4);
        }
    }

    // ---- bias + store (coalesced dwordx4)
    #pragma unroll
    for (int i = 0; i < 4; ++i) {
        const float4 b4 = *reinterpret_cast<const float4*>(bias + i * 256 + lane * 4);
        #pragma unroll
        for (int r = 0; r < ROWS; ++r) {
            if (row0 + r < batch) {
                float4 o;
                o.x = v[r][i*4+0] + b4.x;
                o.y = v[r][i*4+1] + b4.y;
                o.z = v[r][i*4+2] + b4.z;
                o.w = v[r][i*4+3] + b4.w;
                *reinterpret_cast<float4*>(out + (size_t)(row0 + r) * N + i * 256 + lane * 4) = o;
            }
        }
    }
}

extern "C" void kernel_launch(void* const* d_in, const int* in_sizes, int n_in,
                              void* d_out, int out_size, void* d_ws, size_t ws_size,
                              hipStream_t stream)
{
    (void)n_in; (void)d_ws; (void)ws_size; (void)out_size;
    const float* x    = (const float*)d_in[0];
    const float* tw   = (const float*)d_in[1];
    const float* bias = (const float*)d_in[2];
    float* out        = (float*)d_out;

    const int batch = in_sizes[0] / N;
    const int rows_per_block = WAVES * ROWS;      // 32
    const int blocks = (batch + rows_per_block - 1) / rows_per_block;
    hipLaunchKernelGGL(butterfly_kernel, dim3(blocks), dim3(WAVES * 64), 0, stream,
                       x, tw, bias, out, batch);
}